// Round 14
// baseline (122.457 us; speedup 1.0000x reference)
//
#include <hip/hip_runtime.h>
#include <hip/hip_bf16.h>
#include <stdint.h>

typedef uint32_t u32;
typedef uint64_t u64;
typedef __bf16 bf16x8 __attribute__((ext_vector_type(8)));
typedef float f32x4 __attribute__((ext_vector_type(4)));
typedef u32 u32x4 __attribute__((ext_vector_type(4)));

#define NB 8
#define NN 2048
#define DIN 256
#define DOUT 256
#define NR 4
#define KTOT (NN * NR)  // 8192

#define XW_BYTES   (NB * DOUT * KTOT * 2)          // 33,554,432
#define PART_BYTES (NB * NN * DOUT * 4)            // 16,777,216 (f32, fallback)
#define WT_BYTES   (NR * DIN * DOUT * 2)           // 524,288
#define PART_ELEMS (NB * NN * DOUT)                // 4,194,304

__device__ __forceinline__ ushort f2bf(float f) {
  union { float f; u32 u; } c; c.f = f;
  return (ushort)((c.u + 0x7FFFu + ((c.u >> 16) & 1u)) >> 16);
}

__device__ __forceinline__ float bf2f(ushort u) {
  union { u32 i; float f; } c; c.i = ((u32)u) << 16; return c.f;
}

__device__ __forceinline__ void gload_lds16(const void* g, void* l) {
  __builtin_amdgcn_global_load_lds(
      (const __attribute__((address_space(1))) u32*)g,
      (__attribute__((address_space(3))) u32*)l, 16, 0, 0);
}

// ---------------- kernel 0: wT[r][o][d] = bf16(w[r][d][o]) ----------------
__global__ void k0_wT(const float* __restrict__ w, ushort* __restrict__ wT) {
  int i = blockIdx.x * 256 + threadIdx.x;   // 262144 total
  int o = i & 255, d = (i >> 8) & 255, r = i >> 16;
  wT[(r * DOUT + o) * DIN + d] = f2bf(w[i]);
}

// ===== kernel 1 v2 (R13): pipelined + conflict-free LDS ===================
__global__ __launch_bounds__(512) void k1_xw(const float* __restrict__ x,
                                             const ushort* __restrict__ wT,
                                             ushort* __restrict__ xwT) {
  __shared__ char smem[73728];
  char* const Ab0 = smem;            // 4KB  [64 m][32 d] bf16, swizzled
  char* const Ab1 = smem + 4096;
  char* const Bb0 = smem + 8192;     // 32KB [4 r][128 o][32 d] bf16, swizzled
  char* const Bb1 = smem + 40960;
  const int t = threadIdx.x, l = t & 63, w = t >> 6;
  const int r = w >> 1, oh = w & 1;
  const int blk = blockIdx.x;
  const int b = blk >> 6, rest = blk & 63, mc = rest >> 1, ot = rest & 1;

  f32x4 acc[4][4] = {};
  const int fr = l & 15, fq = l >> 4;
  const int ru = ((fq ^ (fr & 3)) << 4);  // swizzled 16B-unit byte offset

  const int arow = t >> 3;
  const int abyte = ((((t & 7) >> 1) ^ (arow & 3)) << 4) + (t & 1) * 8;
  const float* xg = x + ((size_t)(b * NN + mc * 64 + arow) * DIN + (t & 7) * 4);

  const int bdd = (((t & 3) ^ ((t >> 2) & 3)) << 3);
  const int bro = (t >> 2);  // o within 128

#define K1_GLDB(D0, BB)                                                        \
  {                                                                            \
    _Pragma("unroll") for (int i = 0; i < 4; ++i) {                            \
      const ushort* src = wT + ((size_t)(i * DOUT + ot * 128 + bro) * DIN +    \
                                (D0) + bdd);                                   \
      gload_lds16(src, (BB) + i * 8192 + t * 16);                              \
    }                                                                          \
  }

#define K1_WRA(AB, XV)                                                         \
  {                                                                            \
    ushort4 a4;                                                                \
    a4.x = f2bf((XV).x); a4.y = f2bf((XV).y);                                  \
    a4.z = f2bf((XV).z); a4.w = f2bf((XV).w);                                  \
    *(ushort4*)((AB) + arow * 64 + abyte) = a4;                                \
  }

#define K1_MFMA(AB, BB)                                                        \
  {                                                                            \
    bf16x8 af[4];                                                              \
    __builtin_amdgcn_s_setprio(1);                                             \
    _Pragma("unroll") for (int fm = 0; fm < 4; ++fm)                           \
      af[fm] = *(const bf16x8*)((AB) + (fm * 16 + fr) * 64 + ru);              \
    _Pragma("unroll") for (int fo = 0; fo < 4; ++fo) {                         \
      bf16x8 bf = *(const bf16x8*)((BB) + (size_t)(r * 128 + oh * 64 +         \
                                   fo * 16 + fr) * 64 + ru);                   \
      _Pragma("unroll") for (int fm = 0; fm < 4; ++fm)                         \
        acc[fm][fo] = __builtin_amdgcn_mfma_f32_16x16x32_bf16(                 \
            af[fm], bf, acc[fm][fo], 0, 0, 0);                                 \
    }                                                                          \
    __builtin_amdgcn_s_setprio(0);                                             \
  }

#define K1_ENDF()                                                              \
  asm volatile("s_waitcnt vmcnt(0) lgkmcnt(0)" ::: "memory");                  \
  __builtin_amdgcn_s_barrier();                                                \
  __builtin_amdgcn_sched_barrier(0);

#define K1_STEP(S, AP, BP, AQ, BQ)                                             \
  {                                                                            \
    K1_GLDB((S + 1) * 32, BQ);                                                 \
    __builtin_amdgcn_sched_barrier(0);                                         \
    float4 xv = *(const float4*)(xg + (S + 1) * 32);                           \
    K1_MFMA(AP, BP);                                                           \
    K1_WRA(AQ, xv);                                                            \
    K1_ENDF();                                                                 \
  }

  K1_GLDB(0, Bb0);
  __builtin_amdgcn_sched_barrier(0);
  {
    float4 xv = *(const float4*)(xg);
    K1_WRA(Ab0, xv);
  }
  K1_ENDF();

  K1_STEP(0, Ab0, Bb0, Ab1, Bb1);
  K1_STEP(1, Ab1, Bb1, Ab0, Bb0);
  K1_STEP(2, Ab0, Bb0, Ab1, Bb1);
  K1_STEP(3, Ab1, Bb1, Ab0, Bb0);
  K1_STEP(4, Ab0, Bb0, Ab1, Bb1);
  K1_STEP(5, Ab1, Bb1, Ab0, Bb0);
  K1_STEP(6, Ab0, Bb0, Ab1, Bb1);
  K1_MFMA(Ab1, Bb1);  // step 7, no staging
  __syncthreads();

  ushort* Cs = (ushort*)smem;
#pragma unroll
  for (int fm = 0; fm < 4; ++fm)
#pragma unroll
    for (int fo = 0; fo < 4; ++fo)
#pragma unroll
      for (int j = 0; j < 4; ++j) {
        int o_loc = oh * 64 + fo * 16 + fr;
        int ml = fm * 16 + fq * 4 + j;
        Cs[o_loc * 256 + ml * 4 + r] = f2bf(acc[fm][fo][j]);
      }
  __syncthreads();
#pragma unroll
  for (int i = 0; i < 8; ++i) {
    int el = (i * 512 + t) * 8;
    int o_loc = el >> 8, kp = el & 255;
    *(uint4*)(xwT + (size_t)(b * DOUT + ot * 128 + o_loc) * KTOT + mc * 256 + kp) =
        *(const uint4*)(Cs + el);
  }
#undef K1_STEP
#undef K1_ENDF
#undef K1_MFMA
#undef K1_WRA
#undef K1_GLDB
}

// ===== kernel 2 v7: occupancy-driven re-cut (16 waves/CU) =================
// grid 512 logical: b(8).nt(8).ot(2).ks(4); XCD-swizzled (ot-pairs co-XCD).
// BM=256, BN=128, BK=32. 512 thr = 8 waves (4M x 2N), wave 64n x 64o,
// 4x4 frags of 16x16x32. LDS 48KB: A one-hot bf16 [256][64B] dbuf (reg
// expand, swizzled write) + B [128][64B] dbuf (gload_lds, pre-swz source).
// Swizzle for 64B rows: 16B-unit = fq ^ (fr&3) ^ ((fr>>2)&3) — enumerated
// 2 lanes/slot per 16-lane phase on reads AND writes (free, m136).
// __launch_bounds__(512,4) targets VGPR<=128 -> 2 blocks/CU = 4 waves/SIMD:
// ds_read latency hides behind the other waves' MFMA (m114).
// Single fence per step: vmcnt(1)+lgkm0+barrier (rel(s+2) in flight, T4).
__global__ __launch_bounds__(512, 4) void k2_v7(const int* __restrict__ rel,
                                                const ushort* __restrict__ xwT,
                                                ushort* __restrict__ partb) {
  __shared__ char smem[49152];
  const int t = threadIdx.x, l = t & 63, w = t >> 6;
  const int wm = w >> 1, wn = w & 1;
  const int logical = (blockIdx.x & 7) * 64 + (blockIdx.x >> 3);
  const int b = logical >> 6;
  const int nt = (logical >> 3) & 7;
  const int ot = (logical >> 2) & 1;
  const int ks = logical & 3;

  f32x4 acc[4][4] = {};
  const int fr = l & 15, fq = l >> 4;
  const int runit = ((fq ^ (fr & 3) ^ ((fr >> 2) & 3)) << 4);  // byte offset

  char* const Ab0 = smem;            // 16KB [256 n][64 B] one-hot bf16
  char* const Ab1 = smem + 16384;
  char* const Bb0 = smem + 32768;    // 8KB  [128 o][64 B] bf16
  char* const Bb1 = smem + 40960;

  // rel: thread t: row = t>>1 (0..255), half = t&1 (int4 per step)
  const int arow = t >> 1, half = t & 1;
  const int* relg = rel + ((size_t)(b * NN + nt * 256 + arow)) * NN + ks * 512 + half * 4;
  const u32 awz = ((u32)arow & 3u) ^ (((u32)arow >> 2) & 3u);
  char* const rowA0 = Ab0 + arow * 64;
  char* const rowA1 = Ab1 + arow * 64;

  // B staging: thread t: row = t>>2, holds 16B unit t&3; source pre-swizzled
  const int brow = t >> 2;
  const int bsw = (((t & 3) ^ ((brow & 3) ^ ((brow >> 2) & 3))) << 3);  // elems
  const ushort* xwb = xwT + (size_t)(b * DOUT + ot * 128) * KTOT + ks * 2048;

  int4 rs0, rs1;  // rel(k) lives in set k&1

#define GLD_B(S, BB)                                                           \
  gload_lds16(xwb + (size_t)brow * KTOT + (S) * 32 + bsw, (BB) + t * 16);

#define RELLOAD(S, R) R = *(const int4*)(relg + (S) * 8);

// 4 ints (m = half*4..+3) -> 16 one-hot bf16 -> 2 u32x4 at swizzled units
#define EXPROW(ROWP, V)                                                        \
  {                                                                            \
    u32 sa = ((u32)((V).x - 1) & 3u) * 16u, sb = ((u32)((V).y - 1) & 3u) * 16u;\
    u32 sc = ((u32)((V).z - 1) & 3u) * 16u, sd = ((u32)((V).w - 1) & 3u) * 16u;\
    u64 ha = (V).x ? (0x3F80ull << sa) : 0ull;                                 \
    u64 hb = (V).y ? (0x3F80ull << sb) : 0ull;                                 \
    u64 hc = (V).z ? (0x3F80ull << sc) : 0ull;                                 \
    u64 hd = (V).w ? (0x3F80ull << sd) : 0ull;                                 \
    u32x4 e0 = {(u32)ha, (u32)(ha >> 32), (u32)hb, (u32)(hb >> 32)};           \
    u32x4 e1 = {(u32)hc, (u32)(hc >> 32), (u32)hd, (u32)(hd >> 32)};           \
    *(u32x4*)((ROWP) + ((((u32)(half * 2 + 0)) ^ awz) << 4)) = e0;             \
    *(u32x4*)((ROWP) + ((((u32)(half * 2 + 1)) ^ awz) << 4)) = e1;             \
  }

#define RDA(AV, AB)                                                            \
  _Pragma("unroll") for (int fm = 0; fm < 4; ++fm)                             \
    AV[fm] = *(const bf16x8*)((AB) + (wm * 64 + fm * 16 + fr) * 64 + runit);

#define RDB(BV, BB)                                                            \
  _Pragma("unroll") for (int fo = 0; fo < 4; ++fo)                             \
    BV[fo] = *(const bf16x8*)((BB) + (wn * 64 + fo * 16 + fr) * 64 + runit);

#define MFMA2(FM0, AV, BV)                                                     \
  __builtin_amdgcn_s_setprio(1);                                               \
  _Pragma("unroll") for (int i = 0; i < 2; ++i)                                \
    _Pragma("unroll") for (int fo = 0; fo < 4; ++fo)                           \
      acc[(FM0) + i][fo] = __builtin_amdgcn_mfma_f32_16x16x32_bf16(            \
          AV[(FM0) + i], BV[fo], acc[(FM0) + i][fo], 0, 0, 0);                 \
  __builtin_amdgcn_s_setprio(0);

#define ENDF(VMS)                                                              \
  asm volatile("s_waitcnt vmcnt(" VMS ") lgkmcnt(0)" ::: "memory");            \
  __builtin_amdgcn_s_barrier();                                                \
  __builtin_amdgcn_sched_barrier(0);

// One K-step. P = S&1. Stage B(S+1)->BbQ; rel(S+2)->rsP (after gld, order
// pinned); expand A(S+1) from rsQ mid-step; fence keeps rel(s+2) in flight.
#define STEP(S, P, Q, STG, REL, EXP, VMS)                                      \
  {                                                                            \
    bf16x8 av[4], bv[4];                                                       \
    RDB(bv, Bb##P);                                                            \
    RDA(av, Ab##P);                                                            \
    if (STG) { GLD_B((S) + 1, Bb##Q); }                                        \
    __builtin_amdgcn_sched_barrier(0);                                         \
    if (REL) { RELLOAD((S) + 2, rs##P); }                                      \
    __builtin_amdgcn_sched_barrier(0);                                         \
    MFMA2(0, av, bv);                                                          \
    if (EXP) { EXPROW(rowA##Q, rs##Q); }                                       \
    MFMA2(2, av, bv);                                                          \
    ENDF(VMS);                                                                 \
  }

  // prologue: B(0) staged; rel(0),rel(1) loaded; A(0) expanded
  GLD_B(0, Bb0);
  __builtin_amdgcn_sched_barrier(0);
  RELLOAD(0, rs0);
  RELLOAD(1, rs1);
  EXPROW(rowA0, rs0);   // compiler auto-waits rel(0) (retires B(0) too)
  ENDF("1");            // keep rel(1) in flight

  for (int s = 0; s < 62; s += 2) {
    STEP(s, 0, 1, 1, 1, 1, "1");
    STEP(s + 1, 1, 0, 1, 1, 1, "1");
  }
  STEP(62, 0, 1, 1, 0, 1, "0");  // stage B(63), expand A(63) from rs1, drain
  {  // s = 63: final compute, no staging, no fence
    bf16x8 av[4], bv[4];
    RDB(bv, Bb1);
    RDA(av, Ab1);
    MFMA2(0, av, bv);
    MFMA2(2, av, bv);
  }

  ushort* dst = partb + (size_t)ks * PART_ELEMS;
#pragma unroll
  for (int fm = 0; fm < 4; ++fm)
#pragma unroll
    for (int fo = 0; fo < 4; ++fo) {
      int n = nt * 256 + wm * 64 + fm * 16 + fq * 4;
      int o = ot * 128 + wn * 64 + fo * 16 + fr;
#pragma unroll
      for (int j = 0; j < 4; ++j)
        dst[(size_t)(b * NN + n + j) * DOUT + o] = f2bf(acc[fm][fo][j]);
    }
#undef STEP
#undef ENDF
#undef MFMA2
#undef RDB
#undef RDA
#undef EXPROW
#undef RELLOAD
#undef GLD_B
}

// ---------------- kernel 3: out = sum of 4 bf16 partials + bias -----------
__global__ void k3_sum(float* __restrict__ out, const ushort* __restrict__ partb,
                       const float* __restrict__ bias) {
  int i = blockIdx.x * 256 + threadIdx.x;  // float4-group, 1048576 total
  float4 s = ((const float4*)bias)[i & 63];
#pragma unroll
  for (int p = 0; p < 4; ++p) {
    ushort4 v = ((const ushort4*)(partb + (size_t)p * PART_ELEMS))[i];
    s.x += bf2f(v.x); s.y += bf2f(v.y); s.z += bf2f(v.z); s.w += bf2f(v.w);
  }
  ((float4*)out)[i] = s;
}

// ============= fallback path: exact R4 kernels (proven, 50.9MB ws) ========
__global__ __launch_bounds__(256, 2) void k2_r4(const int* __restrict__ rel,
                                                const ushort* __restrict__ xwT,
                                                float* __restrict__ out,
                                                float* __restrict__ part) {
  __shared__ char smem[81920];
  const int t = threadIdx.x, l = t & 63, w = t >> 6;
  const int wr = w >> 1, wc = w & 1;
  const int logical = (blockIdx.x & 7) * 64 + (blockIdx.x >> 3);
  const int b = logical >> 6;
  const int nt = (logical >> 2) & 15;
  const int ks = (logical >> 1) & 1;
  const int ot = logical & 1;

  f32x4 acc[4][4] = {};
  const int arow = t >> 1, half = t & 1;
  const int* relg = rel + ((size_t)(b * NN + nt * 128 + arow) * NN + ks * 1024 + half * 8);
  const ushort* xwb = xwT + (size_t)(b * DOUT + ot * 128) * KTOT + ks * 4096;

  char* const Ab0 = smem;
  char* const Ab1 = smem + 16384;
  char* const Bb0 = smem + 32768;
  char* const Bb1 = smem + 49152;
  char* const Bb2 = smem + 65536;

  const int brow = t >> 3;
  const int kd = (((t & 7) ^ ((t >> 3) & 7)) << 3);
  const int aswz = (arow & 7) << 4;
  const int fr = l & 15, fq = l >> 4;
  const int rswz = (fr & 7) << 4;

  int4 rsA0, rsB0, rsA1, rsB1;

#define STAGE_B(S, BBASE)                                                      \
  {                                                                            \
    _Pragma("unroll") for (int i = 0; i < 4; ++i)                              \
      gload_lds16(xwb + (size_t)(brow + 32 * i) * KTOT + (S) * 64 + kd,        \
                  (BBASE) + i * 4096 + t * 16);                                \
  }
#define RELLOAD(S, RA, RB)                                                     \
  RA = *(const int4*)(relg + (S) * 16);                                        \
  RB = *(const int4*)(relg + (S) * 16 + 4);
#define EXPAND_A(ABASE, V0, V1)                                                \
  {                                                                            \
    char* rowp = (ABASE) + arow * 128;                                         \
    int vv[8] = {V0.x, V0.y, V0.z, V0.w, V1.x, V1.y, V1.z, V1.w};              \
    _Pragma("unroll") for (int p = 0; p < 4; ++p) {                            \
      int va = vv[2 * p], vb = vv[2 * p + 1];                                  \
      u32 sa = ((u32)(va - 1) & 3u) * 16u;                                     \
      u32 sb = ((u32)(vb - 1) & 3u) * 16u;                                     \
      u64 ha = va ? (0x3F80ull << sa) : 0ull;                                  \
      u64 hb = vb ? (0x3F80ull << sb) : 0ull;                                  \
      u32x4 e = {(u32)ha, (u32)(ha >> 32), (u32)hb, (u32)(hb >> 32)};          \
      *(u32x4*)(rowp + ((half * 64 + p * 16) ^ aswz)) = e;                     \
    }                                                                          \
  }
#define BARV6()                                                                \
  asm volatile("s_waitcnt vmcnt(6) lgkmcnt(0)" ::: "memory");                  \
  __builtin_amdgcn_s_barrier();                                                \
  __builtin_amdgcn_sched_barrier(0);
#define BARV0()                                                                \
  asm volatile("s_waitcnt vmcnt(0) lgkmcnt(0)" ::: "memory");                  \
  __builtin_amdgcn_s_barrier();                                                \
  __builtin_amdgcn_sched_barrier(0);
#define MFMA_STEP(AC, BC)                                                      \
  __builtin_amdgcn_s_setprio(1);                                               \
  _Pragma("unroll") for (int kk = 0; kk < 2; ++kk) {                           \
    bf16x8 af[4], bfv[4];                                                      \
    const int colb = (kk * 64 + fq * 16) ^ rswz;                               \
    _Pragma("unroll") for (int fm = 0; fm < 4; ++fm)                           \
      af[fm] = *(const bf16x8*)((AC) + (wr * 64 + fm * 16 + fr) * 128 + colb); \
    _Pragma("unroll") for (int fo = 0; fo < 4; ++fo)                           \
      bfv[fo] = *(const bf16x8*)((BC) + (wc * 64 + fo * 16 + fr) * 128 + colb);\
    _Pragma("unroll") for (int fm = 0; fm < 4; ++fm)                           \
      _Pragma("unroll") for (int fo = 0; fo < 4; ++fo)                         \
        acc[fm][fo] = __builtin_amdgcn_mfma_f32_16x16x32_bf16(                 \
            af[fm], bfv[fo], acc[fm][fo], 0, 0, 0);                            \
  }                                                                            \
  __builtin_amdgcn_s_setprio(0);
#define BODY(S, ACUR, BCUR, ANXT, RLA, RLB, RCA, RCB, BSTG)                    \
  {                                                                            \
    STAGE_B((S) + 2, BSTG);                                                    \
    RELLOAD((S) + 2, RLA, RLB);                                                \
    MFMA_STEP(ACUR, BCUR);                                                     \
    EXPAND_A(ANXT, RCA, RCB);                                                  \
    BARV6();                                                                   \
  }

  STAGE_B(0, Bb0);
  RELLOAD(0, rsA0, rsB0);
  STAGE_B(1, Bb1);
  RELLOAD(1, rsA1, rsB1);
  EXPAND_A(Ab0, rsA0, rsB0);
  BARV6();

  for (int s = 0; s < 60; s += 6) {
    BODY(s + 0, Ab0, Bb0, Ab1, rsA0, rsB0, rsA1, rsB1, Bb2);
    BODY(s + 1, Ab1, Bb1, Ab0, rsA1, rsB1, rsA0, rsB0, Bb0);
    BODY(s + 2, Ab0, Bb2, Ab1, rsA0, rsB0, rsA1, rsB1, Bb1);
    BODY(s + 3, Ab1, Bb0, Ab0, rsA1, rsB1, rsA0, rsB0, Bb2);
    BODY(s + 4, Ab0, Bb1, Ab1, rsA0, rsB0, rsA1, rsB1, Bb0);
    BODY(s + 5, Ab1, Bb2, Ab0, rsA1, rsB1, rsA0, rsB0, Bb1);
  }
  BODY(60, Ab0, Bb0, Ab1, rsA0, rsB0, rsA1, rsB1, Bb2);
  BODY(61, Ab1, Bb1, Ab0, rsA1, rsB1, rsA0, rsB0, Bb0);
  {
    MFMA_STEP(Ab0, Bb2);
    EXPAND_A(Ab1, rsA1, rsB1);
    BARV0();
  }
  {
    MFMA_STEP(Ab1, Bb0);
  }

  float* dst = ks ? part : out;
#pragma unroll
  for (int fm = 0; fm < 4; ++fm)
#pragma unroll
    for (int fo = 0; fo < 4; ++fo) {
      int n = nt * 128 + wr * 64 + fm * 16 + fq * 4;
      int o = ot * 128 + wc * 64 + fo * 16 + fr;
#pragma unroll
      for (int j = 0; j < 4; ++j)
        dst[(size_t)(b * NN + n + j) * DOUT + o] = acc[fm][fo][j];
    }
#undef BODY
#undef MFMA_STEP
#undef BARV6
#undef BARV0
#undef EXPAND_A
#undef RELLOAD
#undef STAGE_B
}

__global__ void k3_r4(float* __restrict__ out, const float* __restrict__ part,
                      const float* __restrict__ bias) {
  int i = blockIdx.x * 256 + threadIdx.x;
  float4 o = ((const float4*)out)[i];
  float4 p = ((const float4*)part)[i];
  float4 bv = ((const float4*)bias)[i & 63];
  float4 rr;
  rr.x = o.x + p.x + bv.x;
  rr.y = o.y + p.y + bv.y;
  rr.z = o.z + p.z + bv.z;
  rr.w = o.w + p.w + bv.w;
  ((float4*)out)[i] = rr;
}

extern "C" void kernel_launch(void* const* d_in, const int* in_sizes, int n_in,
                              void* d_out, int out_size, void* d_ws, size_t ws_size,
                              hipStream_t stream) {
  const float* x = (const float*)d_in[0];
  const int* rel = (const int*)d_in[2];
  const float* wgt = (const float*)d_in[3];
  const float* bias = (const float*)d_in[4];
  float* out = (float*)d_out;
  char* ws = (char*)d_ws;

  const size_t partb_bytes = (size_t)PART_ELEMS * 2 * 4;  // 4 bf16 partials
  const size_t need_big = (size_t)XW_BYTES + partb_bytes + WT_BYTES;
  if (ws_size >= need_big) {
    ushort* xwT = (ushort*)ws;
    ushort* partb = (ushort*)(ws + XW_BYTES);
    ushort* wT = (ushort*)(ws + XW_BYTES + partb_bytes);
    k0_wT<<<1024, 256, 0, stream>>>(wgt, wT);
    k1_xw<<<512, 512, 0, stream>>>(x, wT, xwT);
    k2_v7<<<512, 512, 0, stream>>>(rel, xwT, partb);
    k3_sum<<<4096, 256, 0, stream>>>(out, partb, bias);
  } else {
    ushort* xwT = (ushort*)ws;
    float* part = (float*)(ws + XW_BYTES);
    ushort* wT = (ushort*)(ws + XW_BYTES + PART_BYTES);
    k0_wT<<<1024, 256, 0, stream>>>(wgt, wT);
    k1_xw<<<512, 512, 0, stream>>>(x, wT, xwT);
    k2_r4<<<512, 256, 0, stream>>>(rel, xwT, out, part);
    k3_r4<<<4096, 256, 0, stream>>>(out, part, bias);
  }
}

// Round 15
// 118.352 us; speedup vs baseline: 1.0347x; 1.0347x over previous
//
#include <hip/hip_runtime.h>
#include <hip/hip_bf16.h>
#include <stdint.h>

typedef uint32_t u32;
typedef uint64_t u64;
typedef __bf16 bf16x8 __attribute__((ext_vector_type(8)));
typedef float f32x4 __attribute__((ext_vector_type(4)));
typedef u32 u32x4 __attribute__((ext_vector_type(4)));

#define NB 8
#define NN 2048
#define DIN 256
#define DOUT 256
#define NR 4
#define KTOT (NN * NR)  // 8192

#define XW_BYTES   (NB * DOUT * KTOT * 2)          // 33,554,432
#define PART_BYTES (NB * NN * DOUT * 4)            // 16,777,216 (f32, fallback)
#define WT_BYTES   (NR * DIN * DOUT * 2)           // 524,288
#define PART_ELEMS (NB * NN * DOUT)                // 4,194,304

__device__ __forceinline__ ushort f2bf(float f) {
  union { float f; u32 u; } c; c.f = f;
  return (ushort)((c.u + 0x7FFFu + ((c.u >> 16) & 1u)) >> 16);
}

__device__ __forceinline__ float bf2f(ushort u) {
  union { u32 i; float f; } c; c.i = ((u32)u) << 16; return c.f;
}

__device__ __forceinline__ void gload_lds16(const void* g, void* l) {
  __builtin_amdgcn_global_load_lds(
      (const __attribute__((address_space(1))) u32*)g,
      (__attribute__((address_space(3))) u32*)l, 16, 0, 0);
}

// ---------------- kernel 0: wT[r][o][d] = bf16(w[r][d][o]) ----------------
__global__ void k0_wT(const float* __restrict__ w, ushort* __restrict__ wT) {
  int i = blockIdx.x * 256 + threadIdx.x;   // 262144 total
  int o = i & 255, d = (i >> 8) & 255, r = i >> 16;
  wT[(r * DOUT + o) * DIN + d] = f2bf(w[i]);
}

// ===== kernel 1 v2 (R13): pipelined + conflict-free LDS ===================
__global__ __launch_bounds__(512) void k1_xw(const float* __restrict__ x,
                                             const ushort* __restrict__ wT,
                                             ushort* __restrict__ xwT) {
  __shared__ char smem[73728];
  char* const Ab0 = smem;            // 4KB  [64 m][32 d] bf16, swizzled
  char* const Ab1 = smem + 4096;
  char* const Bb0 = smem + 8192;     // 32KB [4 r][128 o][32 d] bf16, swizzled
  char* const Bb1 = smem + 40960;
  const int t = threadIdx.x, l = t & 63, w = t >> 6;
  const int r = w >> 1, oh = w & 1;
  const int blk = blockIdx.x;
  const int b = blk >> 6, rest = blk & 63, mc = rest >> 1, ot = rest & 1;

  f32x4 acc[4][4] = {};
  const int fr = l & 15, fq = l >> 4;
  const int ru = ((fq ^ (fr & 3)) << 4);  // swizzled 16B-unit byte offset

  const int arow = t >> 3;
  const int abyte = ((((t & 7) >> 1) ^ (arow & 3)) << 4) + (t & 1) * 8;
  const float* xg = x + ((size_t)(b * NN + mc * 64 + arow) * DIN + (t & 7) * 4);

  const int bdd = (((t & 3) ^ ((t >> 2) & 3)) << 3);
  const int bro = (t >> 2);  // o within 128

#define K1_GLDB(D0, BB)                                                        \
  {                                                                            \
    _Pragma("unroll") for (int i = 0; i < 4; ++i) {                            \
      const ushort* src = wT + ((size_t)(i * DOUT + ot * 128 + bro) * DIN +    \
                                (D0) + bdd);                                   \
      gload_lds16(src, (BB) + i * 8192 + t * 16);                              \
    }                                                                          \
  }

#define K1_WRA(AB, XV)                                                         \
  {                                                                            \
    ushort4 a4;                                                                \
    a4.x = f2bf((XV).x); a4.y = f2bf((XV).y);                                  \
    a4.z = f2bf((XV).z); a4.w = f2bf((XV).w);                                  \
    *(ushort4*)((AB) + arow * 64 + abyte) = a4;                                \
  }

#define K1_MFMA(AB, BB)                                                        \
  {                                                                            \
    bf16x8 af[4];                                                              \
    __builtin_amdgcn_s_setprio(1);                                             \
    _Pragma("unroll") for (int fm = 0; fm < 4; ++fm)                           \
      af[fm] = *(const bf16x8*)((AB) + (fm * 16 + fr) * 64 + ru);              \
    _Pragma("unroll") for (int fo = 0; fo < 4; ++fo) {                         \
      bf16x8 bf = *(const bf16x8*)((BB) + (size_t)(r * 128 + oh * 64 +         \
                                   fo * 16 + fr) * 64 + ru);                   \
      _Pragma("unroll") for (int fm = 0; fm < 4; ++fm)                         \
        acc[fm][fo] = __builtin_amdgcn_mfma_f32_16x16x32_bf16(                 \
            af[fm], bf, acc[fm][fo], 0, 0, 0);                                 \
    }                                                                          \
    __builtin_amdgcn_s_setprio(0);                                             \
  }

#define K1_ENDF()                                                              \
  asm volatile("s_waitcnt vmcnt(0) lgkmcnt(0)" ::: "memory");                  \
  __builtin_amdgcn_s_barrier();                                                \
  __builtin_amdgcn_sched_barrier(0);

#define K1_STEP(S, AP, BP, AQ, BQ)                                             \
  {                                                                            \
    K1_GLDB((S + 1) * 32, BQ);                                                 \
    __builtin_amdgcn_sched_barrier(0);                                         \
    float4 xv = *(const float4*)(xg + (S + 1) * 32);                           \
    K1_MFMA(AP, BP);                                                           \
    K1_WRA(AQ, xv);                                                            \
    K1_ENDF();                                                                 \
  }

  K1_GLDB(0, Bb0);
  __builtin_amdgcn_sched_barrier(0);
  {
    float4 xv = *(const float4*)(xg);
    K1_WRA(Ab0, xv);
  }
  K1_ENDF();

  K1_STEP(0, Ab0, Bb0, Ab1, Bb1);
  K1_STEP(1, Ab1, Bb1, Ab0, Bb0);
  K1_STEP(2, Ab0, Bb0, Ab1, Bb1);
  K1_STEP(3, Ab1, Bb1, Ab0, Bb0);
  K1_STEP(4, Ab0, Bb0, Ab1, Bb1);
  K1_STEP(5, Ab1, Bb1, Ab0, Bb0);
  K1_STEP(6, Ab0, Bb0, Ab1, Bb1);
  K1_MFMA(Ab1, Bb1);  // step 7, no staging
  __syncthreads();

  ushort* Cs = (ushort*)smem;
#pragma unroll
  for (int fm = 0; fm < 4; ++fm)
#pragma unroll
    for (int fo = 0; fo < 4; ++fo)
#pragma unroll
      for (int j = 0; j < 4; ++j) {
        int o_loc = oh * 64 + fo * 16 + fr;
        int ml = fm * 16 + fq * 4 + j;
        Cs[o_loc * 256 + ml * 4 + r] = f2bf(acc[fm][fo][j]);
      }
  __syncthreads();
#pragma unroll
  for (int i = 0; i < 8; ++i) {
    int el = (i * 512 + t) * 8;
    int o_loc = el >> 8, kp = el & 255;
    *(uint4*)(xwT + (size_t)(b * DOUT + ot * 128 + o_loc) * KTOT + mc * 256 + kp) =
        *(const uint4*)(Cs + el);
  }
#undef K1_STEP
#undef K1_ENDF
#undef K1_MFMA
#undef K1_WRA
#undef K1_GLDB
}

// ===== kernel 2 v7b: v7 geometry, CORRECTED swizzle (s(row)=(row>>1)&3) ===
// grid 512 logical: b(8).nt(8).ot(2).ks(4); XCD-swizzled (ot-pairs co-XCD).
// BM=256, BN=128, BK=32. 512 thr = 8 waves (4M x 2N), wave 64n x 64o,
// 4x4 frags of 16x16x32. LDS 48KB (2 blocks/CU = 4 waves/SIMD).
// Storage rule: 16B-phys-unit = logical ^ ((row>>1)&3). Enumerated per
// 16-lane quarter-wave: reads 2 lanes/slot, expand-writes 2 lanes/slot,
// gld-B source consistent — all conflict-free (m136: 2-way is free).
// Single fence per step: vmcnt(1)+lgkm0+barrier (rel(s+2) in flight, T4).
__global__ __launch_bounds__(512, 4) void k2_v7(const int* __restrict__ rel,
                                                const ushort* __restrict__ xwT,
                                                ushort* __restrict__ partb) {
  __shared__ char smem[49152];
  const int t = threadIdx.x, l = t & 63, w = t >> 6;
  const int wm = w >> 1, wn = w & 1;
  const int logical = (blockIdx.x & 7) * 64 + (blockIdx.x >> 3);
  const int b = logical >> 6;
  const int nt = (logical >> 3) & 7;
  const int ot = (logical >> 2) & 1;
  const int ks = logical & 3;

  f32x4 acc[4][4] = {};
  const int fr = l & 15, fq = l >> 4;
  const int runit = ((fq ^ ((fr >> 1) & 3)) << 4);  // phys byte offset

  char* const Ab0 = smem;            // 16KB [256 n][64 B] one-hot bf16
  char* const Ab1 = smem + 16384;
  char* const Bb0 = smem + 32768;    // 8KB  [128 o][64 B] bf16
  char* const Bb1 = smem + 40960;

  // rel: thread t: row = t>>1 (0..255), half = t&1 (int4 per step)
  const int arow = t >> 1, half = t & 1;
  const int* relg = rel + ((size_t)(b * NN + nt * 256 + arow)) * NN + ks * 512 + half * 4;
  const u32 awz = (((u32)arow >> 1) & 3u);  // s(row)
  char* const rowA0 = Ab0 + arow * 64;
  char* const rowA1 = Ab1 + arow * 64;

  // B staging: thread t: row = t>>2, phys unit t&3; src holds logical
  // unit (t&3)^s(row), s(row)=((t>>2)>>1)&3=(t>>3)&3 -> pre-swizzled source
  const int brow = t >> 2;
  const int bsw = (((t & 3) ^ ((t >> 3) & 3)) << 3);  // element offset
  const ushort* xwb = xwT + (size_t)(b * DOUT + ot * 128) * KTOT + ks * 2048;

  int4 rs0, rs1;  // rel(k) lives in set k&1

#define GLD_B(S, BB)                                                           \
  gload_lds16(xwb + (size_t)brow * KTOT + (S) * 32 + bsw, (BB) + t * 16);

#define RELLOAD(S, R) R = *(const int4*)(relg + (S) * 8);

// 4 ints (m = half*4..+3) -> 16 one-hot bf16 -> 2 u32x4 at phys units
#define EXPROW(ROWP, V)                                                        \
  {                                                                            \
    u32 sa = ((u32)((V).x - 1) & 3u) * 16u, sb = ((u32)((V).y - 1) & 3u) * 16u;\
    u32 sc = ((u32)((V).z - 1) & 3u) * 16u, sd = ((u32)((V).w - 1) & 3u) * 16u;\
    u64 ha = (V).x ? (0x3F80ull << sa) : 0ull;                                 \
    u64 hb = (V).y ? (0x3F80ull << sb) : 0ull;                                 \
    u64 hc = (V).z ? (0x3F80ull << sc) : 0ull;                                 \
    u64 hd = (V).w ? (0x3F80ull << sd) : 0ull;                                 \
    u32x4 e0 = {(u32)ha, (u32)(ha >> 32), (u32)hb, (u32)(hb >> 32)};           \
    u32x4 e1 = {(u32)hc, (u32)(hc >> 32), (u32)hd, (u32)(hd >> 32)};           \
    *(u32x4*)((ROWP) + ((((u32)(half * 2 + 0)) ^ awz) << 4)) = e0;             \
    *(u32x4*)((ROWP) + ((((u32)(half * 2 + 1)) ^ awz) << 4)) = e1;             \
  }

#define RDA(AV, AB)                                                            \
  _Pragma("unroll") for (int fm = 0; fm < 4; ++fm)                             \
    AV[fm] = *(const bf16x8*)((AB) + (wm * 64 + fm * 16 + fr) * 64 + runit);

#define RDB(BV, BB)                                                            \
  _Pragma("unroll") for (int fo = 0; fo < 4; ++fo)                             \
    BV[fo] = *(const bf16x8*)((BB) + (wn * 64 + fo * 16 + fr) * 64 + runit);

#define MFMA2(FM0, AV, BV)                                                     \
  __builtin_amdgcn_s_setprio(1);                                               \
  _Pragma("unroll") for (int i = 0; i < 2; ++i)                                \
    _Pragma("unroll") for (int fo = 0; fo < 4; ++fo)                           \
      acc[(FM0) + i][fo] = __builtin_amdgcn_mfma_f32_16x16x32_bf16(            \
          AV[(FM0) + i], BV[fo], acc[(FM0) + i][fo], 0, 0, 0);                 \
  __builtin_amdgcn_s_setprio(0);

#define ENDF(VMS)                                                              \
  asm volatile("s_waitcnt vmcnt(" VMS ") lgkmcnt(0)" ::: "memory");            \
  __builtin_amdgcn_s_barrier();                                                \
  __builtin_amdgcn_sched_barrier(0);

// One K-step. P = S&1. Stage B(S+1)->BbQ; rel(S+2)->rsP (after gld, order
// pinned); expand A(S+1) from rsQ mid-step; fence keeps rel(s+2) in flight.
#define STEP(S, P, Q, STG, REL, EXP, VMS)                                      \
  {                                                                            \
    bf16x8 av[4], bv[4];                                                       \
    RDB(bv, Bb##P);                                                            \
    RDA(av, Ab##P);                                                            \
    if (STG) { GLD_B((S) + 1, Bb##Q); }                                        \
    __builtin_amdgcn_sched_barrier(0);                                         \
    if (REL) { RELLOAD((S) + 2, rs##P); }                                      \
    __builtin_amdgcn_sched_barrier(0);                                         \
    MFMA2(0, av, bv);                                                          \
    if (EXP) { EXPROW(rowA##Q, rs##Q); }                                       \
    MFMA2(2, av, bv);                                                          \
    ENDF(VMS);                                                                 \
  }

  // prologue: B(0) staged; rel(0),rel(1) loaded; A(0) expanded
  GLD_B(0, Bb0);
  __builtin_amdgcn_sched_barrier(0);
  RELLOAD(0, rs0);
  RELLOAD(1, rs1);
  EXPROW(rowA0, rs0);   // compiler auto-waits rel(0) (retires B(0) too)
  ENDF("1");            // keep rel(1) in flight

  for (int s = 0; s < 62; s += 2) {
    STEP(s, 0, 1, 1, 1, 1, "1");
    STEP(s + 1, 1, 0, 1, 1, 1, "1");
  }
  STEP(62, 0, 1, 1, 0, 1, "0");  // stage B(63), expand A(63) from rs1, drain
  {  // s = 63: final compute, no staging, no fence
    bf16x8 av[4], bv[4];
    RDB(bv, Bb1);
    RDA(av, Ab1);
    MFMA2(0, av, bv);
    MFMA2(2, av, bv);
  }

  ushort* dst = partb + (size_t)ks * PART_ELEMS;
#pragma unroll
  for (int fm = 0; fm < 4; ++fm)
#pragma unroll
    for (int fo = 0; fo < 4; ++fo) {
      int n = nt * 256 + wm * 64 + fm * 16 + fq * 4;
      int o = ot * 128 + wn * 64 + fo * 16 + fr;
#pragma unroll
      for (int j = 0; j < 4; ++j)
        dst[(size_t)(b * NN + n + j) * DOUT + o] = f2bf(acc[fm][fo][j]);
    }
#undef STEP
#undef ENDF
#undef MFMA2
#undef RDB
#undef RDA
#undef EXPROW
#undef RELLOAD
#undef GLD_B
}

// ---------------- kernel 3: out = sum of 4 bf16 partials + bias -----------
__global__ void k3_sum(float* __restrict__ out, const ushort* __restrict__ partb,
                       const float* __restrict__ bias) {
  int i = blockIdx.x * 256 + threadIdx.x;  // float4-group, 1048576 total
  float4 s = ((const float4*)bias)[i & 63];
#pragma unroll
  for (int p = 0; p < 4; ++p) {
    ushort4 v = ((const ushort4*)(partb + (size_t)p * PART_ELEMS))[i];
    s.x += bf2f(v.x); s.y += bf2f(v.y); s.z += bf2f(v.z); s.w += bf2f(v.w);
  }
  ((float4*)out)[i] = s;
}

// ============= fallback path: exact R4 kernels (proven, 50.9MB ws) ========
__global__ __launch_bounds__(256, 2) void k2_r4(const int* __restrict__ rel,
                                                const ushort* __restrict__ xwT,
                                                float* __restrict__ out,
                                                float* __restrict__ part) {
  __shared__ char smem[81920];
  const int t = threadIdx.x, l = t & 63, w = t >> 6;
  const int wr = w >> 1, wc = w & 1;
  const int logical = (blockIdx.x & 7) * 64 + (blockIdx.x >> 3);
  const int b = logical >> 6;
  const int nt = (logical >> 2) & 15;
  const int ks = (logical >> 1) & 1;
  const int ot = logical & 1;

  f32x4 acc[4][4] = {};
  const int arow = t >> 1, half = t & 1;
  const int* relg = rel + ((size_t)(b * NN + nt * 128 + arow) * NN + ks * 1024 + half * 8);
  const ushort* xwb = xwT + (size_t)(b * DOUT + ot * 128) * KTOT + ks * 4096;

  char* const Ab0 = smem;
  char* const Ab1 = smem + 16384;
  char* const Bb0 = smem + 32768;
  char* const Bb1 = smem + 49152;
  char* const Bb2 = smem + 65536;

  const int brow = t >> 3;
  const int kd = (((t & 7) ^ ((t >> 3) & 7)) << 3);
  const int aswz = (arow & 7) << 4;
  const int fr = l & 15, fq = l >> 4;
  const int rswz = (fr & 7) << 4;

  int4 rsA0, rsB0, rsA1, rsB1;

#define STAGE_B(S, BBASE)                                                      \
  {                                                                            \
    _Pragma("unroll") for (int i = 0; i < 4; ++i)                              \
      gload_lds16(xwb + (size_t)(brow + 32 * i) * KTOT + (S) * 64 + kd,        \
                  (BBASE) + i * 4096 + t * 16);                                \
  }
#define RELLOAD(S, RA, RB)                                                     \
  RA = *(const int4*)(relg + (S) * 16);                                        \
  RB = *(const int4*)(relg + (S) * 16 + 4);
#define EXPAND_A(ABASE, V0, V1)                                                \
  {                                                                            \
    char* rowp = (ABASE) + arow * 128;                                         \
    int vv[8] = {V0.x, V0.y, V0.z, V0.w, V1.x, V1.y, V1.z, V1.w};              \
    _Pragma("unroll") for (int p = 0; p < 4; ++p) {                            \
      int va = vv[2 * p], vb = vv[2 * p + 1];                                  \
      u32 sa = ((u32)(va - 1) & 3u) * 16u;                                     \
      u32 sb = ((u32)(vb - 1) & 3u) * 16u;                                     \
      u64 ha = va ? (0x3F80ull << sa) : 0ull;                                  \
      u64 hb = vb ? (0x3F80ull << sb) : 0ull;                                  \
      u32x4 e = {(u32)ha, (u32)(ha >> 32), (u32)hb, (u32)(hb >> 32)};          \
      *(u32x4*)(rowp + ((half * 64 + p * 16) ^ aswz)) = e;                     \
    }                                                                          \
  }
#define BARV6()                                                                \
  asm volatile("s_waitcnt vmcnt(6) lgkmcnt(0)" ::: "memory");                  \
  __builtin_amdgcn_s_barrier();                                                \
  __builtin_amdgcn_sched_barrier(0);
#define BARV0()                                                                \
  asm volatile("s_waitcnt vmcnt(0) lgkmcnt(0)" ::: "memory");                  \
  __builtin_amdgcn_s_barrier();                                                \
  __builtin_amdgcn_sched_barrier(0);
#define MFMA_STEP(AC, BC)                                                      \
  __builtin_amdgcn_s_setprio(1);                                               \
  _Pragma("unroll") for (int kk = 0; kk < 2; ++kk) {                           \
    bf16x8 af[4], bfv[4];                                                      \
    const int colb = (kk * 64 + fq * 16) ^ rswz;                               \
    _Pragma("unroll") for (int fm = 0; fm < 4; ++fm)                           \
      af[fm] = *(const bf16x8*)((AC) + (wr * 64 + fm * 16 + fr) * 128 + colb); \
    _Pragma("unroll") for (int fo = 0; fo < 4; ++fo)                           \
      bfv[fo] = *(const bf16x8*)((BC) + (wc * 64 + fo * 16 + fr) * 128 + colb);\
    _Pragma("unroll") for (int fm = 0; fm < 4; ++fm)                           \
      _Pragma("unroll") for (int fo = 0; fo < 4; ++fo)                         \
        acc[fm][fo] = __builtin_amdgcn_mfma_f32_16x16x32_bf16(                 \
            af[fm], bfv[fo], acc[fm][fo], 0, 0, 0);                            \
  }                                                                            \
  __builtin_amdgcn_s_setprio(0);
#define BODY(S, ACUR, BCUR, ANXT, RLA, RLB, RCA, RCB, BSTG)                    \
  {                                                                            \
    STAGE_B((S) + 2, BSTG);                                                    \
    RELLOAD((S) + 2, RLA, RLB);                                                \
    MFMA_STEP(ACUR, BCUR);                                                     \
    EXPAND_A(ANXT, RCA, RCB);                                                  \
    BARV6();                                                                   \
  }

  STAGE_B(0, Bb0);
  RELLOAD(0, rsA0, rsB0);
  STAGE_B(1, Bb1);
  RELLOAD(1, rsA1, rsB1);
  EXPAND_A(Ab0, rsA0, rsB0);
  BARV6();

  for (int s = 0; s < 60; s += 6) {
    BODY(s + 0, Ab0, Bb0, Ab1, rsA0, rsB0, rsA1, rsB1, Bb2);
    BODY(s + 1, Ab1, Bb1, Ab0, rsA1, rsB1, rsA0, rsB0, Bb0);
    BODY(s + 2, Ab0, Bb2, Ab1, rsA0, rsB0, rsA1, rsB1, Bb1);
    BODY(s + 3, Ab1, Bb0, Ab0, rsA1, rsB1, rsA0, rsB0, Bb2);
    BODY(s + 4, Ab0, Bb1, Ab1, rsA0, rsB0, rsA1, rsB1, Bb0);
    BODY(s + 5, Ab1, Bb2, Ab0, rsA1, rsB1, rsA0, rsB0, Bb1);
  }
  BODY(60, Ab0, Bb0, Ab1, rsA0, rsB0, rsA1, rsB1, Bb2);
  BODY(61, Ab1, Bb1, Ab0, rsA1, rsB1, rsA0, rsB0, Bb0);
  {
    MFMA_STEP(Ab0, Bb2);
    EXPAND_A(Ab1, rsA1, rsB1);
    BARV0();
  }
  {
    MFMA_STEP(Ab1, Bb0);
  }

  float* dst = ks ? part : out;
#pragma unroll
  for (int fm = 0; fm < 4; ++fm)
#pragma unroll
    for (int fo = 0; fo < 4; ++fo) {
      int n = nt * 128 + wr * 64 + fm * 16 + fq * 4;
      int o = ot * 128 + wc * 64 + fo * 16 + fr;
#pragma unroll
      for (int j = 0; j < 4; ++j)
        dst[(size_t)(b * NN + n + j) * DOUT + o] = acc[fm][fo][j];
    }
#undef BODY
#undef MFMA_STEP
#undef BARV6
#undef BARV0
#undef EXPAND_A
#undef RELLOAD
#undef STAGE_B
}

__global__ void k3_r4(float* __restrict__ out, const float* __restrict__ part,
                      const float* __restrict__ bias) {
  int i = blockIdx.x * 256 + threadIdx.x;
  float4 o = ((const float4*)out)[i];
  float4 p = ((const float4*)part)[i];
  float4 bv = ((const float4*)bias)[i & 63];
  float4 rr;
  rr.x = o.x + p.x + bv.x;
  rr.y = o.y + p.y + bv.y;
  rr.z = o.z + p.z + bv.z;
  rr.w = o.w + p.w + bv.w;
  ((float4*)out)[i] = rr;
}

extern "C" void kernel_launch(void* const* d_in, const int* in_sizes, int n_in,
                              void* d_out, int out_size, void* d_ws, size_t ws_size,
                              hipStream_t stream) {
  const float* x = (const float*)d_in[0];
  const int* rel = (const int*)d_in[2];
  const float* wgt = (const float*)d_in[3];
  const float* bias = (const float*)d_in[4];
  float* out = (float*)d_out;
  char* ws = (char*)d_ws;

  const size_t partb_bytes = (size_t)PART_ELEMS * 2 * 4;  // 4 bf16 partials
  const size_t need_big = (size_t)XW_BYTES + partb_bytes + WT_BYTES;
  if (ws_size >= need_big) {
    ushort* xwT = (ushort*)ws;
    ushort* partb = (ushort*)(ws + XW_BYTES);
    ushort* wT = (ushort*)(ws + XW_BYTES + partb_bytes);
    k0_wT<<<1024, 256, 0, stream>>>(wgt, wT);
    k1_xw<<<512, 512, 0, stream>>>(x, wT, xwT);
    k2_v7<<<512, 512, 0, stream>>>(rel, xwT, partb);
    k3_sum<<<4096, 256, 0, stream>>>(out, partb, bias);
  } else {
    ushort* xwT = (ushort*)ws;
    float* part = (float*)(ws + XW_BYTES);
    ushort* wT = (ushort*)(ws + XW_BYTES + PART_BYTES);
    k0_wT<<<1024, 256, 0, stream>>>(wgt, wT);
    k1_xw<<<512, 512, 0, stream>>>(x, wT, xwT);
    k2_r4<<<512, 256, 0, stream>>>(rel, xwT, out, part);
    k3_r4<<<4096, 256, 0, stream>>>(out, part, bias);
  }
}

// Round 16
// 108.615 us; speedup vs baseline: 1.1274x; 1.0896x over previous
//
#include <hip/hip_runtime.h>
#include <hip/hip_bf16.h>
#include <stdint.h>

typedef uint32_t u32;
typedef uint64_t u64;
typedef __bf16 bf16x8 __attribute__((ext_vector_type(8)));
typedef float f32x4 __attribute__((ext_vector_type(4)));
typedef u32 u32x4 __attribute__((ext_vector_type(4)));

#define NB 8
#define NN 2048
#define DIN 256
#define DOUT 256
#define NR 4
#define KTOT (NN * NR)  // 8192

#define XW_BYTES   (NB * DOUT * KTOT * 2)          // 33,554,432
#define PART_BYTES (NB * NN * DOUT * 4)            // 16,777,216 (f32, fallback)
#define WT_BYTES   (NR * DIN * DOUT * 2)           // 524,288
#define PART_ELEMS (NB * NN * DOUT)                // 4,194,304

__device__ __forceinline__ ushort f2bf(float f) {
  union { float f; u32 u; } c; c.f = f;
  return (ushort)((c.u + 0x7FFFu + ((c.u >> 16) & 1u)) >> 16);
}

__device__ __forceinline__ float bf2f(ushort u) {
  union { u32 i; float f; } c; c.i = ((u32)u) << 16; return c.f;
}

__device__ __forceinline__ void gload_lds16(const void* g, void* l) {
  __builtin_amdgcn_global_load_lds(
      (const __attribute__((address_space(1))) u32*)g,
      (__attribute__((address_space(3))) u32*)l, 16, 0, 0);
}

// ---------------- kernel 0: wT[r][o][d] = bf16(w[r][d][o]) ----------------
__global__ void k0_wT(const float* __restrict__ w, ushort* __restrict__ wT) {
  int i = blockIdx.x * 256 + threadIdx.x;   // 262144 total
  int o = i & 255, d = (i >> 8) & 255, r = i >> 16;
  wT[(r * DOUT + o) * DIN + d] = f2bf(w[i]);
}

// ===== kernel 1 v2 (R13): pipelined + conflict-free LDS ===================
__global__ __launch_bounds__(512) void k1_xw(const float* __restrict__ x,
                                             const ushort* __restrict__ wT,
                                             ushort* __restrict__ xwT) {
  __shared__ char smem[73728];
  char* const Ab0 = smem;            // 4KB  [64 m][32 d] bf16, swizzled
  char* const Ab1 = smem + 4096;
  char* const Bb0 = smem + 8192;     // 32KB [4 r][128 o][32 d] bf16, swizzled
  char* const Bb1 = smem + 40960;
  const int t = threadIdx.x, l = t & 63, w = t >> 6;
  const int r = w >> 1, oh = w & 1;
  const int blk = blockIdx.x;
  const int b = blk >> 6, rest = blk & 63, mc = rest >> 1, ot = rest & 1;

  f32x4 acc[4][4] = {};
  const int fr = l & 15, fq = l >> 4;
  const int ru = ((fq ^ (fr & 3)) << 4);  // swizzled 16B-unit byte offset

  const int arow = t >> 3;
  const int abyte = ((((t & 7) >> 1) ^ (arow & 3)) << 4) + (t & 1) * 8;
  const float* xg = x + ((size_t)(b * NN + mc * 64 + arow) * DIN + (t & 7) * 4);

  const int bdd = (((t & 3) ^ ((t >> 2) & 3)) << 3);
  const int bro = (t >> 2);  // o within 128

#define K1_GLDB(D0, BB)                                                        \
  {                                                                            \
    _Pragma("unroll") for (int i = 0; i < 4; ++i) {                            \
      const ushort* src = wT + ((size_t)(i * DOUT + ot * 128 + bro) * DIN +    \
                                (D0) + bdd);                                   \
      gload_lds16(src, (BB) + i * 8192 + t * 16);                              \
    }                                                                          \
  }

#define K1_WRA(AB, XV)                                                         \
  {                                                                            \
    ushort4 a4;                                                                \
    a4.x = f2bf((XV).x); a4.y = f2bf((XV).y);                                  \
    a4.z = f2bf((XV).z); a4.w = f2bf((XV).w);                                  \
    *(ushort4*)((AB) + arow * 64 + abyte) = a4;                                \
  }

#define K1_MFMA(AB, BB)                                                        \
  {                                                                            \
    bf16x8 af[4];                                                              \
    __builtin_amdgcn_s_setprio(1);                                             \
    _Pragma("unroll") for (int fm = 0; fm < 4; ++fm)                           \
      af[fm] = *(const bf16x8*)((AB) + (fm * 16 + fr) * 64 + ru);              \
    _Pragma("unroll") for (int fo = 0; fo < 4; ++fo) {                         \
      bf16x8 bf = *(const bf16x8*)((BB) + (size_t)(r * 128 + oh * 64 +         \
                                   fo * 16 + fr) * 64 + ru);                   \
      _Pragma("unroll") for (int fm = 0; fm < 4; ++fm)                         \
        acc[fm][fo] = __builtin_amdgcn_mfma_f32_16x16x32_bf16(                 \
            af[fm], bf, acc[fm][fo], 0, 0, 0);                                 \
    }                                                                          \
    __builtin_amdgcn_s_setprio(0);                                             \
  }

#define K1_ENDF()                                                              \
  asm volatile("s_waitcnt vmcnt(0) lgkmcnt(0)" ::: "memory");                  \
  __builtin_amdgcn_s_barrier();                                                \
  __builtin_amdgcn_sched_barrier(0);

#define K1_STEP(S, AP, BP, AQ, BQ)                                             \
  {                                                                            \
    K1_GLDB((S + 1) * 32, BQ);                                                 \
    __builtin_amdgcn_sched_barrier(0);                                         \
    float4 xv = *(const float4*)(xg + (S + 1) * 32);                           \
    K1_MFMA(AP, BP);                                                           \
    K1_WRA(AQ, xv);                                                            \
    K1_ENDF();                                                                 \
  }

  K1_GLDB(0, Bb0);
  __builtin_amdgcn_sched_barrier(0);
  {
    float4 xv = *(const float4*)(xg);
    K1_WRA(Ab0, xv);
  }
  K1_ENDF();

  K1_STEP(0, Ab0, Bb0, Ab1, Bb1);
  K1_STEP(1, Ab1, Bb1, Ab0, Bb0);
  K1_STEP(2, Ab0, Bb0, Ab1, Bb1);
  K1_STEP(3, Ab1, Bb1, Ab0, Bb0);
  K1_STEP(4, Ab0, Bb0, Ab1, Bb1);
  K1_STEP(5, Ab1, Bb1, Ab0, Bb0);
  K1_STEP(6, Ab0, Bb0, Ab1, Bb1);
  K1_MFMA(Ab1, Bb1);  // step 7, no staging
  __syncthreads();

  ushort* Cs = (ushort*)smem;
#pragma unroll
  for (int fm = 0; fm < 4; ++fm)
#pragma unroll
    for (int fo = 0; fo < 4; ++fo)
#pragma unroll
      for (int j = 0; j < 4; ++j) {
        int o_loc = oh * 64 + fo * 16 + fr;
        int ml = fm * 16 + fq * 4 + j;
        Cs[o_loc * 256 + ml * 4 + r] = f2bf(acc[fm][fo][j]);
      }
  __syncthreads();
#pragma unroll
  for (int i = 0; i < 8; ++i) {
    int el = (i * 512 + t) * 8;
    int o_loc = el >> 8, kp = el & 255;
    *(uint4*)(xwT + (size_t)(b * DOUT + ot * 128 + o_loc) * KTOT + mc * 256 + kp) =
        *(const uint4*)(Cs + el);
  }
#undef K1_STEP
#undef K1_ENDF
#undef K1_MFMA
#undef K1_WRA
#undef K1_GLDB
}

// ============= kernel 2 v2 (R8 best, ~935 TF eff): ONE barrier per K-step =
__global__ __launch_bounds__(512, 2) void k2_v2(const int* __restrict__ rel,
                                                const ushort* __restrict__ xwT,
                                                ushort* __restrict__ partb) {
  __shared__ char smem[131072];
  const int t = threadIdx.x, l = t & 63, w = t >> 6;
  const int wm = w >> 2, wn = w & 3;
  const int logical = (blockIdx.x & 7) * 32 + (blockIdx.x >> 3);
  const int b = logical >> 5;
  const int nt = (logical >> 2) & 7;
  const int ks = logical & 3;

  f32x4 acc[8][4] = {};
  const int fr = l & 15, fq = l >> 4;
  const int rswz = (fr & 7) << 4;

  char* const Ab0 = smem;
  char* const Ab1 = smem + 32768;
  char* const Bb0 = smem + 65536;
  char* const Bb1 = smem + 98304;

  const int arow = t >> 1, half = t & 1;
  const int aswz = (arow & 7) << 4;
  const int* relg = rel + ((size_t)(b * NN + nt * 256 + arow)) * NN + ks * 512 + half * 8;

  const int brow = t >> 3;
  const int kd = (((t & 7) ^ ((t >> 3) & 7)) << 3);
  const ushort* xwb = xwT + (size_t)b * DOUT * KTOT + ks * 2048;

  int4 rs0a, rs0b, rs1a, rs1b;

#define GLD_ALL(S, BB)                                                         \
  {                                                                            \
    _Pragma("unroll") for (int i = 0; i < 4; ++i)                              \
      gload_lds16(xwb + (size_t)(brow + 64 * i) * KTOT + (S) * 64 + kd,        \
                  (BB) + i * 8192 + t * 16);                                   \
  }

#define RELLOAD(S, RA, RB)                                                     \
  RA = *(const int4*)(relg + (S) * 16);                                        \
  RB = *(const int4*)(relg + (S) * 16 + 4);

#define EXPAND_A(ABASE, V0, V1)                                                \
  {                                                                            \
    char* rowp = (ABASE) + arow * 128;                                         \
    int vv[8] = {V0.x, V0.y, V0.z, V0.w, V1.x, V1.y, V1.z, V1.w};              \
    _Pragma("unroll") for (int p = 0; p < 4; ++p) {                            \
      int va = vv[2 * p], vb = vv[2 * p + 1];                                  \
      u32 sa = ((u32)(va - 1) & 3u) * 16u;                                     \
      u32 sb = ((u32)(vb - 1) & 3u) * 16u;                                     \
      u64 ha = va ? (0x3F80ull << sa) : 0ull;                                  \
      u64 hb = vb ? (0x3F80ull << sb) : 0ull;                                  \
      u32x4 e = {(u32)ha, (u32)(ha >> 32), (u32)hb, (u32)(hb >> 32)};          \
      *(u32x4*)(rowp + ((half * 64 + p * 16) ^ aswz)) = e;                     \
    }                                                                          \
  }

#define RDB(BV, BB, KK)                                                        \
  _Pragma("unroll") for (int fo = 0; fo < 4; ++fo)                             \
    BV[fo] = *(const bf16x8*)((BB) + (wn * 64 + fo * 16 + fr) * 128 +          \
                              (((KK) * 64 + fq * 16) ^ rswz));

#define RDA(AV, AB, FM0, KK)                                                   \
  _Pragma("unroll") for (int i = 0; i < 4; ++i)                                \
    AV[i] = *(const bf16x8*)((AB) + (wm * 128 + ((FM0) + i) * 16 + fr) * 128 + \
                             (((KK) * 64 + fq * 16) ^ rswz));

#define MFMA4(FM0, AV, BV)                                                     \
  __builtin_amdgcn_s_setprio(1);                                               \
  _Pragma("unroll") for (int i = 0; i < 4; ++i)                                \
    _Pragma("unroll") for (int fo = 0; fo < 4; ++fo)                           \
      acc[(FM0) + i][fo] = __builtin_amdgcn_mfma_f32_16x16x32_bf16(            \
          AV[i], BV[fo], acc[(FM0) + i][fo], 0, 0, 0);                         \
  __builtin_amdgcn_s_setprio(0);

#define ENDFENCE(VMS)                                                          \
  asm volatile("s_waitcnt vmcnt(" VMS ") lgkmcnt(0)" ::: "memory");            \
  __builtin_amdgcn_s_barrier();                                                \
  __builtin_amdgcn_sched_barrier(0);

#define STEP(S, P, Q, STG, REL, EXP, VMS)                                      \
  {                                                                            \
    bf16x8 b0[4], b1[4], aA[4], aB[4], aC[4], aD[4];                           \
    RDB(b0, Bb##P, 0);                                                         \
    RDA(aA, Ab##P, 0, 0);                                                      \
    if (STG) { GLD_ALL((S) + 1, Bb##Q); }                                      \
    __builtin_amdgcn_sched_barrier(0);                                         \
    if (REL) { RELLOAD((S) + 2, rs##P##a, rs##P##b); }                         \
    RDA(aB, Ab##P, 4, 0);                                                      \
    MFMA4(0, aA, b0);                                                          \
    RDA(aC, Ab##P, 0, 1);                                                      \
    if (EXP) { EXPAND_A(Ab##Q, rs##Q##a, rs##Q##b); }                          \
    MFMA4(4, aB, b0);                                                          \
    RDB(b1, Bb##P, 1);                                                         \
    RDA(aD, Ab##P, 4, 1);                                                      \
    MFMA4(0, aC, b1);                                                          \
    MFMA4(4, aD, b1);                                                          \
    ENDFENCE(VMS);                                                             \
  }

  GLD_ALL(0, Bb0);
  __builtin_amdgcn_sched_barrier(0);
  RELLOAD(0, rs0a, rs0b);
  RELLOAD(1, rs1a, rs1b);
  EXPAND_A(Ab0, rs0a, rs0b);
  ENDFENCE("4");

  for (int s = 0; s < 30; s += 2) {
    STEP(s, 0, 1, 1, 1, 1, "2");
    STEP(s + 1, 1, 0, 1, 1, 1, "2");
  }
  STEP(30, 0, 1, 1, 0, 1, "0");
  {  // s = 31: final compute
    bf16x8 b0[4], b1[4], aA[4], aB[4], aC[4], aD[4];
    RDB(b0, Bb1, 0);
    RDA(aA, Ab1, 0, 0);
    RDA(aB, Ab1, 4, 0);
    MFMA4(0, aA, b0);
    RDA(aC, Ab1, 0, 1);
    MFMA4(4, aB, b0);
    RDB(b1, Bb1, 1);
    RDA(aD, Ab1, 4, 1);
    MFMA4(0, aC, b1);
    MFMA4(4, aD, b1);
  }

  ushort* dst = partb + (size_t)ks * PART_ELEMS;
#pragma unroll
  for (int fm = 0; fm < 8; ++fm)
#pragma unroll
    for (int fo = 0; fo < 4; ++fo) {
      int n = nt * 256 + wm * 128 + fm * 16 + fq * 4;
      int o = wn * 64 + fo * 16 + fr;
#pragma unroll
      for (int j = 0; j < 4; ++j)
        dst[(size_t)(b * NN + n + j) * DOUT + o] = f2bf(acc[fm][fo][j]);
    }
#undef STEP
#undef ENDFENCE
#undef MFMA4
#undef RDA
#undef RDB
#undef EXPAND_A
#undef RELLOAD
#undef GLD_ALL
}

// ---------------- kernel 3: out = sum of 4 bf16 partials + bias -----------
__global__ void k3_sum(float* __restrict__ out, const ushort* __restrict__ partb,
                       const float* __restrict__ bias) {
  int i = blockIdx.x * 256 + threadIdx.x;  // float4-group, 1048576 total
  float4 s = ((const float4*)bias)[i & 63];
#pragma unroll
  for (int p = 0; p < 4; ++p) {
    ushort4 v = ((const ushort4*)(partb + (size_t)p * PART_ELEMS))[i];
    s.x += bf2f(v.x); s.y += bf2f(v.y); s.z += bf2f(v.z); s.w += bf2f(v.w);
  }
  ((float4*)out)[i] = s;
}

// ============= fallback path: exact R4 kernels (proven, 50.9MB ws) ========
__global__ __launch_bounds__(256, 2) void k2_r4(const int* __restrict__ rel,
                                                const ushort* __restrict__ xwT,
                                                float* __restrict__ out,
                                                float* __restrict__ part) {
  __shared__ char smem[81920];
  const int t = threadIdx.x, l = t & 63, w = t >> 6;
  const int wr = w >> 1, wc = w & 1;
  const int logical = (blockIdx.x & 7) * 64 + (blockIdx.x >> 3);
  const int b = logical >> 6;
  const int nt = (logical >> 2) & 15;
  const int ks = (logical >> 1) & 1;
  const int ot = logical & 1;

  f32x4 acc[4][4] = {};
  const int arow = t >> 1, half = t & 1;
  const int* relg = rel + ((size_t)(b * NN + nt * 128 + arow) * NN + ks * 1024 + half * 8);
  const ushort* xwb = xwT + (size_t)(b * DOUT + ot * 128) * KTOT + ks * 4096;

  char* const Ab0 = smem;
  char* const Ab1 = smem + 16384;
  char* const Bb0 = smem + 32768;
  char* const Bb1 = smem + 49152;
  char* const Bb2 = smem + 65536;

  const int brow = t >> 3;
  const int kd = (((t & 7) ^ ((t >> 3) & 7)) << 3);
  const int aswz = (arow & 7) << 4;
  const int fr = l & 15, fq = l >> 4;
  const int rswz = (fr & 7) << 4;

  int4 rsA0, rsB0, rsA1, rsB1;

#define STAGE_B(S, BBASE)                                                      \
  {                                                                            \
    _Pragma("unroll") for (int i = 0; i < 4; ++i)                              \
      gload_lds16(xwb + (size_t)(brow + 32 * i) * KTOT + (S) * 64 + kd,        \
                  (BBASE) + i * 4096 + t * 16);                                \
  }
#define RELLOAD(S, RA, RB)                                                     \
  RA = *(const int4*)(relg + (S) * 16);                                        \
  RB = *(const int4*)(relg + (S) * 16 + 4);
#define EXPAND_A(ABASE, V0, V1)                                                \
  {                                                                            \
    char* rowp = (ABASE) + arow * 128;                                         \
    int vv[8] = {V0.x, V0.y, V0.z, V0.w, V1.x, V1.y, V1.z, V1.w};              \
    _Pragma("unroll") for (int p = 0; p < 4; ++p) {                            \
      int va = vv[2 * p], vb = vv[2 * p + 1];                                  \
      u32 sa = ((u32)(va - 1) & 3u) * 16u;                                     \
      u32 sb = ((u32)(vb - 1) & 3u) * 16u;                                     \
      u64 ha = va ? (0x3F80ull << sa) : 0ull;                                  \
      u64 hb = vb ? (0x3F80ull << sb) : 0ull;                                  \
      u32x4 e = {(u32)ha, (u32)(ha >> 32), (u32)hb, (u32)(hb >> 32)};          \
      *(u32x4*)(rowp + ((half * 64 + p * 16) ^ aswz)) = e;                     \
    }                                                                          \
  }
#define BARV6()                                                                \
  asm volatile("s_waitcnt vmcnt(6) lgkmcnt(0)" ::: "memory");                  \
  __builtin_amdgcn_s_barrier();                                                \
  __builtin_amdgcn_sched_barrier(0);
#define BARV0()                                                                \
  asm volatile("s_waitcnt vmcnt(0) lgkmcnt(0)" ::: "memory");                  \
  __builtin_amdgcn_s_barrier();                                                \
  __builtin_amdgcn_sched_barrier(0);
#define MFMA_STEP(AC, BC)                                                      \
  __builtin_amdgcn_s_setprio(1);                                               \
  _Pragma("unroll") for (int kk = 0; kk < 2; ++kk) {                           \
    bf16x8 af[4], bfv[4];                                                      \
    const int colb = (kk * 64 + fq * 16) ^ rswz;                               \
    _Pragma("unroll") for (int fm = 0; fm < 4; ++fm)                           \
      af[fm] = *(const bf16x8*)((AC) + (wr * 64 + fm * 16 + fr) * 128 + colb); \
    _Pragma("unroll") for (int fo = 0; fo < 4; ++fo)                           \
      bfv[fo] = *(const bf16x8*)((BC) + (wc * 64 + fo * 16 + fr) * 128 + colb);\
    _Pragma("unroll") for (int fm = 0; fm < 4; ++fm)                           \
      _Pragma("unroll") for (int fo = 0; fo < 4; ++fo)                         \
        acc[fm][fo] = __builtin_amdgcn_mfma_f32_16x16x32_bf16(                 \
            af[fm], bfv[fo], acc[fm][fo], 0, 0, 0);                            \
  }                                                                            \
  __builtin_amdgcn_s_setprio(0);
#define BODY(S, ACUR, BCUR, ANXT, RLA, RLB, RCA, RCB, BSTG)                    \
  {                                                                            \
    STAGE_B((S) + 2, BSTG);                                                    \
    RELLOAD((S) + 2, RLA, RLB);                                                \
    MFMA_STEP(ACUR, BCUR);                                                     \
    EXPAND_A(ANXT, RCA, RCB);                                                  \
    BARV6();                                                                   \
  }

  STAGE_B(0, Bb0);
  RELLOAD(0, rsA0, rsB0);
  STAGE_B(1, Bb1);
  RELLOAD(1, rsA1, rsB1);
  EXPAND_A(Ab0, rsA0, rsB0);
  BARV6();

  for (int s = 0; s < 60; s += 6) {
    BODY(s + 0, Ab0, Bb0, Ab1, rsA0, rsB0, rsA1, rsB1, Bb2);
    BODY(s + 1, Ab1, Bb1, Ab0, rsA1, rsB1, rsA0, rsB0, Bb0);
    BODY(s + 2, Ab0, Bb2, Ab1, rsA0, rsB0, rsA1, rsB1, Bb1);
    BODY(s + 3, Ab1, Bb0, Ab0, rsA1, rsB1, rsA0, rsB0, Bb2);
    BODY(s + 4, Ab0, Bb1, Ab1, rsA0, rsB0, rsA1, rsB1, Bb0);
    BODY(s + 5, Ab1, Bb2, Ab0, rsA1, rsB1, rsA0, rsB0, Bb1);
  }
  BODY(60, Ab0, Bb0, Ab1, rsA0, rsB0, rsA1, rsB1, Bb2);
  BODY(61, Ab1, Bb1, Ab0, rsA1, rsB1, rsA0, rsB0, Bb0);
  {
    MFMA_STEP(Ab0, Bb2);
    EXPAND_A(Ab1, rsA1, rsB1);
    BARV0();
  }
  {
    MFMA_STEP(Ab1, Bb0);
  }

  float* dst = ks ? part : out;
#pragma unroll
  for (int fm = 0; fm < 4; ++fm)
#pragma unroll
    for (int fo = 0; fo < 4; ++fo) {
      int n = nt * 128 + wr * 64 + fm * 16 + fq * 4;
      int o = ot * 128 + wc * 64 + fo * 16 + fr;
#pragma unroll
      for (int j = 0; j < 4; ++j)
        dst[(size_t)(b * NN + n + j) * DOUT + o] = acc[fm][fo][j];
    }
#undef BODY
#undef MFMA_STEP
#undef BARV6
#undef BARV0
#undef EXPAND_A
#undef RELLOAD
#undef STAGE_B
}

__global__ void k3_r4(float* __restrict__ out, const float* __restrict__ part,
                      const float* __restrict__ bias) {
  int i = blockIdx.x * 256 + threadIdx.x;
  float4 o = ((const float4*)out)[i];
  float4 p = ((const float4*)part)[i];
  float4 bv = ((const float4*)bias)[i & 63];
  float4 rr;
  rr.x = o.x + p.x + bv.x;
  rr.y = o.y + p.y + bv.y;
  rr.z = o.z + p.z + bv.z;
  rr.w = o.w + p.w + bv.w;
  ((float4*)out)[i] = rr;
}

extern "C" void kernel_launch(void* const* d_in, const int* in_sizes, int n_in,
                              void* d_out, int out_size, void* d_ws, size_t ws_size,
                              hipStream_t stream) {
  const float* x = (const float*)d_in[0];
  const int* rel = (const int*)d_in[2];
  const float* wgt = (const float*)d_in[3];
  const float* bias = (const float*)d_in[4];
  float* out = (float*)d_out;
  char* ws = (char*)d_ws;

  const size_t partb_bytes = (size_t)PART_ELEMS * 2 * 4;  // 4 bf16 partials
  const size_t need_big = (size_t)XW_BYTES + partb_bytes + WT_BYTES;
  if (ws_size >= need_big) {
    ushort* xwT = (ushort*)ws;
    ushort* partb = (ushort*)(ws + XW_BYTES);
    ushort* wT = (ushort*)(ws + XW_BYTES + partb_bytes);
    k0_wT<<<1024, 256, 0, stream>>>(wgt, wT);
    k1_xw<<<512, 512, 0, stream>>>(x, wT, xwT);
    k2_v2<<<256, 512, 0, stream>>>(rel, xwT, partb);
    k3_sum<<<4096, 256, 0, stream>>>(out, partb, bias);
  } else {
    ushort* xwT = (ushort*)ws;
    float* part = (float*)(ws + XW_BYTES);
    ushort* wT = (ushort*)(ws + XW_BYTES + PART_BYTES);
    k0_wT<<<1024, 256, 0, stream>>>(wgt, wT);
    k1_xw<<<512, 512, 0, stream>>>(x, wT, xwT);
    k2_r4<<<512, 256, 0, stream>>>(rel, xwT, out, part);
    k3_r4<<<4096, 256, 0, stream>>>(out, part, bias);
  }
}